// Round 6
// baseline (494.936 us; speedup 1.0000x reference)
//
#include <hip/hip_runtime.h>

// B=2, T=2048, C=2048, H=32, KVH=8, HD=64, N_REP=4. Inputs fp32, output fp32.
// cast x -> bf16; transpose-cast W; QKV GEMM (global_load_lds, +RoPE +Q-scale-fold, +V^T);
// flash attn v4 (1024 blocks, 3 blocks/CU via launch_bounds, 32q/wave, KVBLK=64,
// K self-prefetch, V-hoist, defer-max, swizzled LDS P, XCD-resident K/V); out-proj GEMM.

typedef short short8 __attribute__((ext_vector_type(8)));
typedef float f32x4  __attribute__((ext_vector_type(4)));

#define QSCALE 0.18033688011112042f  /* 0.125 * log2(e): S' = log2e * (q.k/8) */

__device__ __forceinline__ unsigned short f2bf(float x) {
  union { float f; unsigned u; } v; v.f = x;
  unsigned r = v.u + 0x7FFFu + ((v.u >> 16) & 1u);
  return (unsigned short)(r >> 16);
}

#if __has_builtin(__builtin_amdgcn_exp2f)
#define EXP2(x) __builtin_amdgcn_exp2f(x)
#else
#define EXP2(x) exp2f(x)
#endif

__device__ __forceinline__ void gload16(const unsigned short* g, unsigned short* l) {
  __builtin_amdgcn_global_load_lds((const __attribute__((address_space(1))) void*)g,
                                   (__attribute__((address_space(3))) void*)l, 16, 0, 0);
}

// ---------------- cast x (fp32 -> bf16) ----------------
__global__ __launch_bounds__(256) void cast_x_kernel(const float* __restrict__ in,
                                                     unsigned short* __restrict__ out, int n4) {
  int i = blockIdx.x * 256 + threadIdx.x;
  if (i >= n4) return;
  float4 v = ((const float4*)in)[i];
  ushort4 o; o.x = f2bf(v.x); o.y = f2bf(v.y); o.z = f2bf(v.z); o.w = f2bf(v.w);
  ((ushort4*)out)[i] = o;
}

// ------------- W[K=2048][N] fp32 -> Wt[N][2048] bf16 -------------
__global__ __launch_bounds__(256) void transpose_cast(const float* __restrict__ W,
                                                      unsigned short* __restrict__ Wt,
                                                      int Ncols) {
  __shared__ float tile[32][33];
  const int nt = blockIdx.x, kt = blockIdx.y;
  const int lr = threadIdx.x >> 5, lc = threadIdx.x & 31;
  #pragma unroll
  for (int p = 0; p < 4; ++p) {
    int row = kt * 32 + lr + p * 8;
    tile[lr + p * 8][lc] = W[(size_t)row * Ncols + nt * 32 + lc];
  }
  __syncthreads();
  #pragma unroll
  for (int p = 0; p < 4; ++p) {
    int n = nt * 32 + lr + p * 8;
    Wt[(size_t)n * 2048 + kt * 32 + lc] = f2bf(tile[lc][lr + p * 8]);
  }
}

// ---------------- 128x128-tile bf16 GEMM via global_load_lds ----------------
__global__ __launch_bounds__(256) void gemm128(const unsigned short* __restrict__ A,
                                               const unsigned short* __restrict__ Wt,
                                               const float* __restrict__ freq,
                                               float* __restrict__ outP,
                                               unsigned short* __restrict__ Qb,
                                               unsigned short* __restrict__ Kb,
                                               unsigned short* __restrict__ Vt,
                                               int kind) {
  __shared__ __align__(16) unsigned short As[128 * 32];
  __shared__ __align__(16) unsigned short Bs[128 * 32];
  const int tid = threadIdx.x;
  const int lane = tid & 63;
  const int wave = tid >> 6;
  const int mb = blockIdx.x, nb = blockIdx.y;
  const int m0w = (wave >> 1) * 64, n0w = (wave & 1) * 64;

  f32x4 acc[4][4];
  #pragma unroll
  for (int i = 0; i < 4; ++i)
    #pragma unroll
    for (int j = 0; j < 4; ++j)
      #pragma unroll
      for (int t = 0; t < 4; ++t) acc[i][j][t] = 0.f;

  const int ca = tid, cb = tid + 256;
  const size_t aoff0 = (size_t)(mb * 128 + (ca >> 2)) * 2048 + (ca & 3) * 8;
  const size_t aoff1 = (size_t)(mb * 128 + (cb >> 2)) * 2048 + (cb & 3) * 8;
  const size_t boff0 = (size_t)(nb * 128 + (ca >> 2)) * 2048 + (ca & 3) * 8;
  const size_t boff1 = (size_t)(nb * 128 + (cb >> 2)) * 2048 + (cb & 3) * 8;

  for (int k0 = 0; k0 < 2048; k0 += 32) {
    __syncthreads();
    gload16(A + aoff0 + k0, &As[ca * 8]);
    gload16(A + aoff1 + k0, &As[cb * 8]);
    gload16(Wt + boff0 + k0, &Bs[ca * 8]);
    gload16(Wt + boff1 + k0, &Bs[cb * 8]);
    __syncthreads();
    short8 af[4], bfr[4];
    #pragma unroll
    for (int i = 0; i < 4; ++i) {
      af[i]  = *(const short8*)&As[(m0w + i * 16 + (lane & 15)) * 32 + (lane >> 4) * 8];
      bfr[i] = *(const short8*)&Bs[(n0w + i * 16 + (lane & 15)) * 32 + (lane >> 4) * 8];
    }
    #pragma unroll
    for (int i = 0; i < 4; ++i)
      #pragma unroll
      for (int j = 0; j < 4; ++j)
        acc[i][j] = __builtin_amdgcn_mfma_f32_16x16x32_bf16(af[i], bfr[j], acc[i][j], 0, 0, 0);
  }

  // C frag: row = (lane>>4)*4 + t, col = lane&15
  const int colbase = n0w + (lane & 15);
  const int rowbase = mb * 128 + m0w + (lane >> 4) * 4;
  if (kind == 0) {
    #pragma unroll
    for (int i = 0; i < 4; ++i)
      #pragma unroll
      for (int j = 0; j < 4; ++j) {
        int col = nb * 128 + colbase + j * 16;
        #pragma unroll
        for (int t = 0; t < 4; ++t)
          outP[(size_t)(rowbase + i * 16 + t) * 2048 + col] = acc[i][j][t];
      }
  } else {
    #pragma unroll
    for (int i = 0; i < 4; ++i) {
      #pragma unroll
      for (int j = 0; j < 4; ++j) {
        int ncolg = nb * 128 + colbase + j * 16;
        f32x4 v = acc[i][j];
        if (ncolg < 2560) {                        // Q or K: RoPE
          float pv[4];
          #pragma unroll
          for (int t = 0; t < 4; ++t) pv[t] = __shfl_xor(v[t], 1);
          const int ii = (ncolg & 63) >> 1;
          const bool evn = (ncolg & 1) == 0;
          #pragma unroll
          for (int t = 0; t < 4; ++t) {
            int gm = rowbase + i * 16 + t;
            int token = gm & 2047;
            float cc = freq[(token * 32 + ii) * 2];
            float ss = freq[(token * 32 + ii) * 2 + 1];
            float o = evn ? (v[t] * cc - pv[t] * ss) : (v[t] * cc + pv[t] * ss);
            if (ncolg < 2048) Qb[(size_t)gm * 2048 + ncolg] = f2bf(o * QSCALE);
            else              Kb[(size_t)gm * 512 + (ncolg - 2048)] = f2bf(o);
          }
        } else {                                   // V: transposed store Vt[b][kvh][d][token]
          int vc = ncolg - 2560;
          int kvh = vc >> 6, d = vc & 63;
          int gm0 = rowbase + i * 16;
          int bb = gm0 >> 11, token0 = gm0 & 2047;
          ushort4 pk;
          pk.x = f2bf(v[0]); pk.y = f2bf(v[1]); pk.z = f2bf(v[2]); pk.w = f2bf(v[3]);
          *(ushort4*)&Vt[((size_t)((bb * 8 + kvh) * 64 + d)) * 2048 + token0] = pk;
        }
      }
    }
  }
}

// -------- flash attention v4: 1024 blocks (1 chunk each, work-descending),
// __launch_bounds__(256,3) for 3 blocks/CU, K self-prefetch into same regs,
// V-hoist, defer-max, swizzled LDS P bounce, XCD-resident K/V --------
__global__ __launch_bounds__(256, 3) void attn_kernel(const unsigned short* __restrict__ Qb,
                                                      const unsigned short* __restrict__ Kb,
                                                      const unsigned short* __restrict__ Vt,
                                                      unsigned short* __restrict__ AO) {
  __shared__ __align__(16) char P_raw[4][4096];   // per-wave [qi][16 q][64 kv] bf16, XOR-swizzled
  const int lane = threadIdx.x & 63;
  const int wave = threadIdx.x >> 6;
  // XCD decode: blkid&7 == kvh -> all blocks sharing one (b,kvh) K/V set land on one XCD.
  const int blkid = blockIdx.x;
  const int kvh = blkid & 7;
  const int s   = blkid >> 3;        // 0..127
  const int b   = s >> 6;
  const int hg  = (s >> 4) & 3;
  const int qc  = 15 - (s & 15);     // work-descending launch order
  const int h   = kvh * 4 + hg;
  const int ql = lane & 15, g = lane >> 4;
  const int swz = (ql & 7) << 4;
  char* pbase = P_raw[wave];
  const unsigned short* kbase = Kb + (size_t)(b * 2048) * 512 + kvh * 64;
  const unsigned short* vbase = Vt + (size_t)((b * 8 + kvh) * 64) * 2048;

  const int q0w = qc * 128 + wave * 32;
  short8 qf[2][2];
  #pragma unroll
  for (int qi = 0; qi < 2; ++qi)
    #pragma unroll
    for (int s2 = 0; s2 < 2; ++s2)
      qf[qi][s2] = *(const short8*)(Qb + (size_t)(b * 2048 + q0w + qi * 16 + ql) * 2048 +
                                    h * 64 + s2 * 32 + g * 8);
  f32x4 oacc[4][2];
  #pragma unroll
  for (int dt = 0; dt < 4; ++dt)
    #pragma unroll
    for (int qi = 0; qi < 2; ++qi)
      #pragma unroll
      for (int t = 0; t < 4; ++t) oacc[dt][qi][t] = 0.f;
  float m0 = -3e38f, m1 = -3e38f, l0 = 0.f, l1 = 0.f;

  const int nkb = (q0w >> 6) + 1;
  short8 kf[4][2];
  #pragma unroll
  for (int kt = 0; kt < 4; ++kt)
    #pragma unroll
    for (int s2 = 0; s2 < 2; ++s2)
      kf[kt][s2] = *(const short8*)(kbase + (size_t)(kt * 16 + ql) * 512 + s2 * 32 + g * 8);

  for (int kb = 0; kb < nkb; ++kb) {
    const int kv0 = kb * 64;
    f32x4 sacc[4][2];
    #pragma unroll
    for (int kt = 0; kt < 4; ++kt)
      #pragma unroll
      for (int qi = 0; qi < 2; ++qi)
        #pragma unroll
        for (int t = 0; t < 4; ++t) sacc[kt][qi][t] = 0.f;
    __builtin_amdgcn_s_setprio(1);
    #pragma unroll
    for (int kt = 0; kt < 4; ++kt)
      #pragma unroll
      for (int s2 = 0; s2 < 2; ++s2)
        #pragma unroll
        for (int qi = 0; qi < 2; ++qi)
          sacc[kt][qi] = __builtin_amdgcn_mfma_f32_16x16x32_bf16(kf[kt][s2], qf[qi][s2],
                                                                 sacc[kt][qi], 0, 0, 0);
    __builtin_amdgcn_s_setprio(0);
    // K self-prefetch: overwrite kf with next tile (WAR vs issued MFMAs is safe;
    // latency hides under softmax + PV below)
    if (kb + 1 < nkb) {
      #pragma unroll
      for (int kt = 0; kt < 4; ++kt)
        #pragma unroll
        for (int s2 = 0; s2 < 2; ++s2)
          kf[kt][s2] = *(const short8*)(kbase + (size_t)(kv0 + 64 + kt * 16 + ql) * 512 +
                                        s2 * 32 + g * 8);
    }
    // hoist V loads: issued here, consumed after softmax
    short8 vf[4][2];
    #pragma unroll
    for (int dt = 0; dt < 4; ++dt)
      #pragma unroll
      for (int c = 0; c < 2; ++c)
        vf[dt][c] = *(const short8*)(vbase + (size_t)(dt * 16 + ql) * 2048 + kv0 +
                                     c * 32 + g * 8);
    if (kb == nkb - 1) {          // causal mask on diagonal tile
      #pragma unroll
      for (int kt = 0; kt < 4; ++kt)
        #pragma unroll
        for (int qi = 0; qi < 2; ++qi)
          #pragma unroll
          for (int t = 0; t < 4; ++t) {
            int kv = kv0 + kt * 16 + 4 * g + t;
            if (kv > q0w + qi * 16 + ql) sacc[kt][qi][t] = -1e30f;
          }
    }
    float bm0 = sacc[0][0][0], bm1 = sacc[0][1][0];
    #pragma unroll
    for (int kt = 0; kt < 4; ++kt)
      #pragma unroll
      for (int t = 0; t < 4; ++t) {
        bm0 = fmaxf(bm0, sacc[kt][0][t]);
        bm1 = fmaxf(bm1, sacc[kt][1][t]);
      }
    bm0 = fmaxf(bm0, __shfl_xor(bm0, 16)); bm0 = fmaxf(bm0, __shfl_xor(bm0, 32));
    bm1 = fmaxf(bm1, __shfl_xor(bm1, 16)); bm1 = fmaxf(bm1, __shfl_xor(bm1, 32));
    if (!__all(bm0 <= m0 + 8.f && bm1 <= m1 + 8.f)) {   // defer-max (T13, log2 units)
      float mn0 = fmaxf(m0, bm0), mn1 = fmaxf(m1, bm1);
      float a0 = EXP2(m0 - mn0), a1 = EXP2(m1 - mn1);
      m0 = mn0; m1 = mn1; l0 *= a0; l1 *= a1;
      #pragma unroll
      for (int dt = 0; dt < 4; ++dt)
        #pragma unroll
        for (int t = 0; t < 4; ++t) { oacc[dt][0][t] *= a0; oacc[dt][1][t] *= a1; }
    }
    float ps0 = 0.f, ps1 = 0.f;
    #pragma unroll
    for (int kt = 0; kt < 4; ++kt)
      #pragma unroll
      for (int t = 0; t < 4; ++t) {
        float e0 = EXP2(sacc[kt][0][t] - m0); sacc[kt][0][t] = e0; ps0 += e0;
        float e1 = EXP2(sacc[kt][1][t] - m1); sacc[kt][1][t] = e1; ps1 += e1;
      }
    ps0 += __shfl_xor(ps0, 16); ps0 += __shfl_xor(ps0, 32);
    ps1 += __shfl_xor(ps1, 16); ps1 += __shfl_xor(ps1, 32);
    l0 += ps0; l1 += ps1;

    #pragma unroll
    for (int qi = 0; qi < 2; ++qi)
      #pragma unroll
      for (int kt = 0; kt < 4; ++kt) {
        uint2 w;
        w.x = (unsigned)f2bf(sacc[kt][qi][0]) | ((unsigned)f2bf(sacc[kt][qi][1]) << 16);
        w.y = (unsigned)f2bf(sacc[kt][qi][2]) | ((unsigned)f2bf(sacc[kt][qi][3]) << 16);
        *(uint2*)(pbase + qi * 2048 + ((ql * 128 + kt * 32 + g * 8) ^ swz)) = w;
      }
    short8 pf[2][2];
    #pragma unroll
    for (int qi = 0; qi < 2; ++qi)
      #pragma unroll
      for (int c = 0; c < 2; ++c)
        pf[qi][c] = *(const short8*)(pbase + qi * 2048 + ((ql * 128 + c * 64 + g * 16) ^ swz));
    __builtin_amdgcn_s_setprio(1);
    #pragma unroll
    for (int dt = 0; dt < 4; ++dt)
      #pragma unroll
      for (int c = 0; c < 2; ++c)
        #pragma unroll
        for (int qi = 0; qi < 2; ++qi)
          oacc[dt][qi] = __builtin_amdgcn_mfma_f32_16x16x32_bf16(vf[dt][c], pf[qi][c],
                                                                 oacc[dt][qi], 0, 0, 0);
    __builtin_amdgcn_s_setprio(0);
  }

  const float inv0 = 1.f / l0, inv1 = 1.f / l1;
  #pragma unroll
  for (int qi = 0; qi < 2; ++qi) {
    const float inv = qi ? inv1 : inv0;
    unsigned short* ao = AO + (size_t)(b * 2048 + q0w + qi * 16 + ql) * 2048 + h * 64;
    #pragma unroll
    for (int dt = 0; dt < 4; ++dt) {
      ushort4 pk;
      pk.x = f2bf(oacc[dt][qi][0] * inv); pk.y = f2bf(oacc[dt][qi][1] * inv);
      pk.z = f2bf(oacc[dt][qi][2] * inv); pk.w = f2bf(oacc[dt][qi][3] * inv);
      *(ushort4*)&ao[dt * 16 + 4 * g] = pk;
    }
  }
}

extern "C" void kernel_launch(void* const* d_in, const int* in_sizes, int n_in,
                              void* d_out, int out_size, void* d_ws, size_t ws_size,
                              hipStream_t stream) {
  const float* x    = (const float*)d_in[0];
  const float* freq = (const float*)d_in[1];
  const float* Wq = (const float*)d_in[4];
  const float* Wk = (const float*)d_in[5];
  const float* Wv = (const float*)d_in[6];
  const float* Wo = (const float*)d_in[7];
  float* out = (float*)d_out;

  char* ws = (char*)d_ws;
  unsigned short* xb   = (unsigned short*)(ws);             // [4096][2048] bf16, 16.78 MB
  unsigned short* Wqkv = (unsigned short*)(ws + 16777216);  // [3072][2048] bf16, 12.58 MB
  unsigned short* Qb   = (unsigned short*)(ws + 29360128);  // [4096][2048] bf16 (pre-scaled)
  unsigned short* Kb   = (unsigned short*)(ws + 46137344);  // [4096][512]  bf16
  unsigned short* Vt   = (unsigned short*)(ws + 50331648);  // [2][8][64][2048]
  unsigned short* AO   = xb;                                // alias: x dead after QKV GEMM
  unsigned short* Wot  = Wqkv;                              // alias: Wqkv dead after QKV GEMM

  cast_x_kernel<<<8192, 256, 0, stream>>>(x, xb, 2097152);
  transpose_cast<<<dim3(64, 64), 256, 0, stream>>>(Wq, Wqkv, 2048);
  transpose_cast<<<dim3(16, 64), 256, 0, stream>>>(Wk, Wqkv + (size_t)2048 * 2048, 512);
  transpose_cast<<<dim3(16, 64), 256, 0, stream>>>(Wv, Wqkv + (size_t)2560 * 2048, 512);
  gemm128<<<dim3(32, 24), 256, 0, stream>>>(xb, Wqkv, freq, nullptr, Qb, Kb, Vt, 1);
  transpose_cast<<<dim3(64, 64), 256, 0, stream>>>(Wo, Wot, 2048);
  attn_kernel<<<1024, 256, 0, stream>>>(Qb, Kb, Vt, AO);
  gemm128<<<dim3(32, 16), 256, 0, stream>>>(AO, Wot, freq, out, nullptr, nullptr, nullptr, 0);
}